// Round 6
// baseline (327.498 us; speedup 1.0000x reference)
//
#include <hip/hip_runtime.h>

// MultiSpectralDCTLayer: Y = W @ X @ W^T per (b,c) tile, then radial band mask.
// XOR bug in the mask => s = (i^2)+(j^2) (bitwise XOR), s_max = 222.
//   c=0 keeps s < 196 (most entries), c=1 keeps s >= 196, c>=2 keeps nothing.
// Sharper: max over j of (j^2) is 111, so c=1 keeps entries only where
// (i^2) >= 85, i.e. only rows i >= 84 (chunk q=3). c=1 chunks q<3 are pure fill.
//
// Grid: 512 "compute" blocks first (128 tiles x 4 row-chunks of 28 rows; 192 of
// them degrade to chunk-fills), then 3968 pure-fill blocks. One kernel so fill
// writes overlap compute. LDS 24.5 KB -> 6 blocks/CU.

#define SIZE  112
#define TILE  (SIZE * SIZE)    // 12544
#define TILE4 (TILE / 4)       // 3136
#define ROW4  (SIZE / 4)       // 28
#define NCOMPUTE 512
#define FILLV 1e-8f

#define DOT4(a, b) ((a).x*(b).x + (a).y*(b).y + (a).z*(b).z + (a).w*(b).w)
// NOTE: param must not be named 'w'/'x'/'y'/'z' — macro args substitute even
// after '.', so '(u).w' would expand with the arg text (round-5 compile fail).
#define ACC4(u, wc, xv) { (u).x += (wc)*(xv).x; (u).y += (wc)*(xv).y; \
                          (u).z += (wc)*(xv).z; (u).w += (wc)*(xv).w; }

__global__ __launch_bounds__(256)
void dct_band_kernel(const float* __restrict__ x,
                     const float* __restrict__ W,
                     float* __restrict__ out)
{
    const int tid = threadIdx.x;
    const int blk = blockIdx.x;
    const float4 fillv = make_float4(FILLV, FILLV, FILLV, FILLV);

    if (blk >= NCOMPUTE) {
        // ---- pure fill: groups c>=2 are 1e-8 everywhere ----
        const int f = blk - NCOMPUTE;
        const int b = f / 62;
        const int c = 2 + f % 62;
        float4* o4 = (float4*)(out + (size_t)(b * 64 + c) * TILE);
        #pragma unroll
        for (int n = 0; n < 13; ++n) {
            int e = tid + n * 256;
            if (e < TILE4) o4[e] = fillv;
        }
        return;
    }

    const int q  = blk & 3;          // row chunk: rows i0..i0+27
    const int t  = blk >> 2;         // tile 0..127
    const int b  = t >> 1;
    const int c  = t & 1;
    const int i0 = 28 * q;
    const size_t tOff = (size_t)(b * 64 + c) * TILE;

    if (c == 1 && q < 3) {
        // rows i < 84 have (i^2) <= 83 < 85, so no c=1 entry survives: chunk fill.
        float4* o4 = (float4*)(out + tOff + (size_t)i0 * SIZE);
        #pragma unroll
        for (int n = 0; n < 4; ++n) {
            int e = tid + n * 256;
            if (e < 784) o4[e] = fillv;
        }
        return;
    }

    // ---- compute path ----
    __shared__ float4 Xs[784];    // one 28-row K-panel of X: 12544 B
    __shared__ float4 Usm[784];   // U[di][l4], row stride 28 float4s: 12544 B

    const float4* x4 = (const float4*)(x + tOff);

    // Stage A: U[i0+di][l] = sum_k W[i0+di][k] * X[k][l], K in 4 panels of 28.
    // thread (diq, l4): 4 di rows x 4 l cols; 196 active threads.
    // W rows read as float4 (b128) -> 4x fewer VMEM than scalar walk.
    const int diq = tid / 28;
    const int l4  = tid % 28;
    float4 u0 = make_float4(0,0,0,0), u1 = u0, u2 = u0, u3 = u0;

    for (int kp = 0; kp < 4; ++kp) {
        // load X panel (rows kp*28 .. kp*28+27) -> LDS, coalesced float4
        #pragma unroll
        for (int n = 0; n < 4; ++n) {
            int e = tid + n * 256;
            if (e < 784) Xs[e] = x4[kp * 784 + e];
        }
        __syncthreads();

        if (tid < 196) {
            const float4* w40 = (const float4*)(W + (i0 + 4 * diq) * SIZE) + kp * 7;
            const float4* w41 = w40 + ROW4;
            const float4* w42 = w41 + ROW4;
            const float4* w43 = w42 + ROW4;
            #pragma unroll
            for (int k4 = 0; k4 < 7; ++k4) {
                float4 wv0 = w40[k4], wv1 = w41[k4], wv2 = w42[k4], wv3 = w43[k4];
                float4 xv0 = Xs[(4*k4 + 0) * 28 + l4];
                float4 xv1 = Xs[(4*k4 + 1) * 28 + l4];
                float4 xv2 = Xs[(4*k4 + 2) * 28 + l4];
                float4 xv3 = Xs[(4*k4 + 3) * 28 + l4];
                ACC4(u0, wv0.x, xv0) ACC4(u0, wv0.y, xv1) ACC4(u0, wv0.z, xv2) ACC4(u0, wv0.w, xv3)
                ACC4(u1, wv1.x, xv0) ACC4(u1, wv1.y, xv1) ACC4(u1, wv1.z, xv2) ACC4(u1, wv1.w, xv3)
                ACC4(u2, wv2.x, xv0) ACC4(u2, wv2.y, xv1) ACC4(u2, wv2.z, xv2) ACC4(u2, wv2.w, xv3)
                ACC4(u3, wv3.x, xv0) ACC4(u3, wv3.y, xv1) ACC4(u3, wv3.z, xv2) ACC4(u3, wv3.w, xv3)
            }
        }
        __syncthreads();   // Xs reads done before next panel overwrites
    }

    if (tid < 196) {
        const int ub = 4 * diq * 28 + l4;
        Usm[ub]      = u0;
        Usm[ub + 28] = u1;
        Usm[ub + 56] = u2;
        Usm[ub + 84] = u3;
    }
    __syncthreads();

    // Stage B: Y[i][j] = sum_l U[i][l] * W[j][l], then mask + store.
    // thread (dq, jq): 4 i rows x 4 j cols. U broadcast from LDS; W rows
    // walked as float4 from L1 (W is 50 KB, shared by all blocks).
    if (tid < 196) {
        const int dq = tid / 28;
        const int jq = tid % 28;
        float acc[4][4];
        #pragma unroll
        for (int a = 0; a < 4; ++a)
            #pragma unroll
            for (int d = 0; d < 4; ++d) acc[a][d] = 0.f;

        const float4* Ur = Usm + 4 * dq * 28;
        const float4* W4 = (const float4*)W;
        const float4* w0 = W4 + (4 * jq + 0) * ROW4;
        const float4* w1 = W4 + (4 * jq + 1) * ROW4;
        const float4* w2 = W4 + (4 * jq + 2) * ROW4;
        const float4* w3 = W4 + (4 * jq + 3) * ROW4;
        #pragma unroll 2
        for (int l = 0; l < 28; ++l) {
            float4 uv0 = Ur[l], uv1 = Ur[l + 28], uv2 = Ur[l + 56], uv3 = Ur[l + 84];
            float4 wv0 = w0[l], wv1 = w1[l], wv2 = w2[l], wv3 = w3[l];
            acc[0][0] += DOT4(uv0, wv0); acc[0][1] += DOT4(uv0, wv1);
            acc[0][2] += DOT4(uv0, wv2); acc[0][3] += DOT4(uv0, wv3);
            acc[1][0] += DOT4(uv1, wv0); acc[1][1] += DOT4(uv1, wv1);
            acc[1][2] += DOT4(uv1, wv2); acc[1][3] += DOT4(uv1, wv3);
            acc[2][0] += DOT4(uv2, wv0); acc[2][1] += DOT4(uv2, wv1);
            acc[2][2] += DOT4(uv2, wv2); acc[2][3] += DOT4(uv2, wv3);
            acc[3][0] += DOT4(uv3, wv0); acc[3][1] += DOT4(uv3, wv1);
            acc[3][2] += DOT4(uv3, wv2); acc[3][3] += DOT4(uv3, wv3);
        }

        const int j0 = 4 * jq;
        const bool g1 = (c != 0);
        #pragma unroll
        for (int mi = 0; mi < 4; ++mi) {
            const int i  = i0 + 4 * dq + mi;
            const int xi = i ^ 2;
            float4 res;
            res.x = (((xi + ((j0 + 0) ^ 2)) < 196) != g1) ? acc[mi][0] : FILLV;
            res.y = (((xi + ((j0 + 1) ^ 2)) < 196) != g1) ? acc[mi][1] : FILLV;
            res.z = (((xi + ((j0 + 2) ^ 2)) < 196) != g1) ? acc[mi][2] : FILLV;
            res.w = (((xi + ((j0 + 3) ^ 2)) < 196) != g1) ? acc[mi][3] : FILLV;
            ((float4*)(out + tOff + (size_t)i * SIZE))[jq] = res;
        }
    }
}

extern "C" void kernel_launch(void* const* d_in, const int* in_sizes, int n_in,
                              void* d_out, int out_size, void* d_ws, size_t ws_size,
                              hipStream_t stream) {
    const float* x = (const float*)d_in[0];
    const float* W = (const float*)d_in[1];
    float* out = (float*)d_out;
    (void)in_sizes; (void)n_in; (void)out_size; (void)d_ws; (void)ws_size;
    dct_band_kernel<<<dim3(NCOMPUTE + 64 * 62), dim3(256), 0, stream>>>(x, W, out);
}